// Round 1
// baseline (2617.078 us; speedup 1.0000x reference)
//
#include <hip/hip_runtime.h>
#include <math.h>

// Model dims
#define NZc     64
#define EMBEDc  256
#define DMc     256
#define NHc     16
#define HDc     16
#define DFFc    1024
#define NLc     6
#define E1Dc    32
#define PDIMc   64
#define PMAXLc  24
#define NBINSc  49
#define NB      8
#define Lc      512
#define NTOK    (NB * Lc)   // 4096
#define UMDIM   (EMBEDc + E1Dc)  // 288

// ---------------------------------------------------------------------------
// K1: per-layer per-head per-bin attention bias:
//     bb[l][h][bin] = dot(pos_emb[bin], W2d[l][h]) + b2d[l][h]
__global__ void k_biasbins(const float* __restrict__ pos_emb,
                           const float* __restrict__ W2d,
                           const float* __restrict__ b2d,
                           float* __restrict__ bb) {
    int idx = blockIdx.x * blockDim.x + threadIdx.x;
    if (idx >= NLc * NHc * NBINSc) return;
    int bin = idx % NBINSc;
    int tmp = idx / NBINSc;
    int hh = tmp % NHc;
    int l  = tmp / NHc;
    float s = b2d[l * NHc + hh];
    const float* pe = pos_emb + bin * PDIMc;
    const float* w  = W2d + (l * NHc + hh) * PDIMc;
    for (int p = 0; p < PDIMc; ++p) s += pe[p] * w[p];
    bb[idx] = s;
}

// ---------------------------------------------------------------------------
// K2: e_aa[tok] = aa_emb[argmax_c x[n, c, l]]
__global__ void k_eaa(const float* __restrict__ x,
                      const float* __restrict__ aa_emb,
                      float* __restrict__ e_aa) {
    int tok = blockIdx.x * blockDim.x + threadIdx.x;
    if (tok >= NTOK) return;
    int n = tok / Lc, l = tok % Lc;
    const float* xp = x + (size_t)n * 20 * Lc + l;
    float best = xp[0];
    int bi = 0;
    for (int c = 1; c < 20; ++c) {
        float v = xp[c * Lc];
        if (v > best) { best = v; bi = c; }   // first-max semantics
    }
    const float* e = aa_emb + bi * E1Dc;
    float* o = e_aa + (size_t)tok * E1Dc;
    for (int c = 0; c < E1Dc; ++c) o[c] = e[c];
}

// ---------------------------------------------------------------------------
// K3: token embed: h = relu(z^T @ W1^T + b1) @ W2^T + b2   (one block / token)
__global__ __launch_bounds__(256) void k_embed(const float* __restrict__ z,
                                               const float* __restrict__ w1,
                                               const float* __restrict__ b1,
                                               const float* __restrict__ w2,
                                               const float* __restrict__ b2,
                                               float* __restrict__ h) {
    int tok = blockIdx.x;
    int t = threadIdx.x;
    int n = tok / Lc, l = tok % Lc;
    __shared__ float zs[NZc];
    __shared__ float hid[EMBEDc];
    if (t < NZc) zs[t] = z[((size_t)n * NZc + t) * Lc + l];
    __syncthreads();
    float s = b1[t];
    const float* w = w1 + t * NZc;
    for (int c = 0; c < NZc; ++c) s += zs[c] * w[c];
    hid[t] = fmaxf(s, 0.0f);
    __syncthreads();
    s = b2[t];
    const float* wr = w2 + t * EMBEDc;
    for (int c = 0; c < EMBEDc; ++c) s += hid[c] * wr[c];
    h[(size_t)tok * EMBEDc + t] = s;
}

// ---------------------------------------------------------------------------
// K4: 256x256 projection for a 16-token tile; out = (h @ W^T) * scale
//     grid.x = NTOK/16, 256 threads, thread t owns out-dim t, 16 accumulators.
__global__ __launch_bounds__(256) void k_qkv(const float* __restrict__ h,
                                             const float* __restrict__ W,
                                             float* __restrict__ out,
                                             float scale) {
    int tile = blockIdx.x;
    int t = threadIdx.x;
    __shared__ float hs[16][EMBEDc];
    for (int u = t; u < 16 * EMBEDc; u += 256)
        hs[u >> 8][u & 255] = h[(size_t)tile * 16 * EMBEDc + u];
    __syncthreads();
    float acc[16];
#pragma unroll
    for (int i = 0; i < 16; ++i) acc[i] = 0.f;
    const float* wr = W + (size_t)t * EMBEDc;
    for (int c = 0; c < EMBEDc; ++c) {
        float wv = wr[c];
#pragma unroll
        for (int i = 0; i < 16; ++i) acc[i] += hs[i][c] * wv;
    }
    for (int i = 0; i < 16; ++i)
        out[((size_t)tile * 16 + i) * EMBEDc + t] = acc[i] * scale;
}

// ---------------------------------------------------------------------------
// K5: attention for one (n, head, 16-query-row tile). bb pre-offset to layer.
__global__ __launch_bounds__(256) void k_attn(const float* __restrict__ q,
                                              const float* __restrict__ k,
                                              const float* __restrict__ v,
                                              const float* __restrict__ bb,
                                              float* __restrict__ o) {
    int blk = blockIdx.x;
    int it   = blk & 31;          // Lc/16 = 32 tiles
    int head = (blk >> 5) & 15;
    int n    = blk >> 9;
    int t = threadIdx.x;
    int rr = t >> 4, c = t & 15;
    int i = it * 16 + rr;

    __shared__ float sc[16][Lc + 4];   // padded stride 516 -> no bank conflict
    __shared__ float tile[64][HDc];
    __shared__ float qs[16][HDc];
    __shared__ float biasr[NBINSc];

    if (t < NBINSc) biasr[t] = bb[head * NBINSc + t];
    qs[rr][c] = q[((size_t)n * Lc + i) * DMc + head * HDc + c];
    __syncthreads();

    // scores
    for (int jt = 0; jt < 8; ++jt) {
        for (int u = t; u < 64 * HDc; u += 256) {
            int jj = u >> 4, dd = u & 15;
            tile[jj][dd] = k[((size_t)n * Lc + jt * 64 + jj) * DMc + head * HDc + dd];
        }
        __syncthreads();
        for (int jj = c; jj < 64; jj += 16) {
            float s = 0.f;
#pragma unroll
            for (int dd = 0; dd < HDc; ++dd) s += qs[rr][dd] * tile[jj][dd];
            int j = jt * 64 + jj;
            int rel = j - i;
            rel = rel < -PMAXLc ? -PMAXLc : (rel > PMAXLc ? PMAXLc : rel);
            sc[rr][j] = s + biasr[rel + PMAXLc];
        }
        __syncthreads();
    }

    // softmax over row rr (threads c = 0..15 of that row)
    float m = -1e30f;
    for (int j = c; j < Lc; j += 16) m = fmaxf(m, sc[rr][j]);
#pragma unroll
    for (int off = 8; off; off >>= 1) m = fmaxf(m, __shfl_xor(m, off, 16));
    float sum = 0.f;
    for (int j = c; j < Lc; j += 16) {
        float e = __expf(sc[rr][j] - m);
        sc[rr][j] = e;
        sum += e;
    }
#pragma unroll
    for (int off = 8; off; off >>= 1) sum += __shfl_xor(sum, off, 16);
    float inv = 1.0f / sum;
    __syncthreads();

    // PV: thread (rr, c) computes o[i][head*16 + c]
    float acc = 0.f;
    for (int jt = 0; jt < 8; ++jt) {
        for (int u = t; u < 64 * HDc; u += 256) {
            int jj = u >> 4, dd = u & 15;
            tile[jj][dd] = v[((size_t)n * Lc + jt * 64 + jj) * DMc + head * HDc + dd];
        }
        __syncthreads();
#pragma unroll
        for (int jj = 0; jj < 64; ++jj) acc += sc[rr][jt * 64 + jj] * tile[jj][c];
        __syncthreads();
    }
    o[((size_t)n * Lc + i) * DMc + head * HDc + c] = acc * inv;
}

// ---------------------------------------------------------------------------
// K6: s2 = o @ Wo^T + bo ; h = LN(h + s2)  (16 tokens / block)
__global__ __launch_bounds__(256) void k_oproj_ln(const float* __restrict__ o,
                                                  const float* __restrict__ Wo,
                                                  const float* __restrict__ bo,
                                                  const float* __restrict__ g,
                                                  const float* __restrict__ bta,
                                                  float* __restrict__ h) {
    int tile = blockIdx.x;
    int t = threadIdx.x;
    __shared__ float ov[16][EMBEDc];
    __shared__ float s2s[16][EMBEDc + 4];
    for (int u = t; u < 16 * EMBEDc; u += 256)
        ov[u >> 8][u & 255] = o[(size_t)tile * 16 * EMBEDc + u];
    __syncthreads();
    float acc[16];
#pragma unroll
    for (int i = 0; i < 16; ++i) acc[i] = 0.f;
    const float* wr = Wo + (size_t)t * DMc;
    for (int c = 0; c < DMc; ++c) {
        float wv = wr[c];
#pragma unroll
        for (int i = 0; i < 16; ++i) acc[i] += ov[i][c] * wv;
    }
    float bias = bo[t];
    for (int i = 0; i < 16; ++i) s2s[i][t] = acc[i] + bias;
    __syncthreads();
    // LayerNorm: thread -> (tok = t>>4, j = t&15), each handles 16 dims
    int tok = t >> 4, j = t & 15;
    size_t gtok = (size_t)tile * 16 + tok;
    float sum = 0.f, ssq = 0.f;
    float vals[16];
#pragma unroll
    for (int d0 = 0; d0 < 16; ++d0) {
        int d = j + d0 * 16;
        float vv = h[gtok * EMBEDc + d] + s2s[tok][d];
        vals[d0] = vv;
        sum += vv;
        ssq += vv * vv;
    }
#pragma unroll
    for (int off = 8; off; off >>= 1) {
        sum += __shfl_xor(sum, off, 16);
        ssq += __shfl_xor(ssq, off, 16);
    }
    float mean = sum * (1.f / EMBEDc);
    float var  = ssq * (1.f / EMBEDc) - mean * mean;
    float inv = rsqrtf(var + 1e-5f);
#pragma unroll
    for (int d0 = 0; d0 < 16; ++d0) {
        int d = j + d0 * 16;
        h[gtok * EMBEDc + d] = (vals[d0] - mean) * inv * g[d] + bta[d];
    }
}

// ---------------------------------------------------------------------------
// K7: FFN (288 -> 1024 relu -> 256) + residual + LN  (16 tokens / block)
__global__ __launch_bounds__(256) void k_ffn_ln(const float* __restrict__ h,
                                                const float* __restrict__ e_aa,
                                                const float* __restrict__ Wf1,
                                                const float* __restrict__ bf1,
                                                const float* __restrict__ Wf2,
                                                const float* __restrict__ bf2,
                                                const float* __restrict__ g,
                                                const float* __restrict__ bta,
                                                float* __restrict__ hout) {
    int tile = blockIdx.x;
    int t = threadIdx.x;
    __shared__ float um[16][UMDIM];
    __shared__ float hc[16][EMBEDc + 4];
    __shared__ float s2s[16][EMBEDc + 4];
    for (int u = t; u < 16 * EMBEDc; u += 256)
        um[u >> 8][u & 255] = h[(size_t)tile * 16 * EMBEDc + u];
    for (int u = t; u < 16 * E1Dc; u += 256)
        um[u >> 5][EMBEDc + (u & 31)] = e_aa[(size_t)tile * 16 * E1Dc + u];
    __syncthreads();

    float out[16];
    float b2v = bf2[t];
#pragma unroll
    for (int i = 0; i < 16; ++i) out[i] = b2v;
    const float* w2r = Wf2 + (size_t)t * DFFc;

    for (int chunk = 0; chunk < 4; ++chunk) {
        int hd = chunk * 256 + t;
        float hid[16];
        float b1v = bf1[hd];
#pragma unroll
        for (int i = 0; i < 16; ++i) hid[i] = b1v;
        const float* w1r = Wf1 + (size_t)hd * UMDIM;
        for (int c = 0; c < UMDIM; ++c) {
            float wv = w1r[c];
#pragma unroll
            for (int i = 0; i < 16; ++i) hid[i] += um[i][c] * wv;
        }
        __syncthreads();   // previous chunk's hc reads complete
#pragma unroll
        for (int i = 0; i < 16; ++i) hc[i][t] = fmaxf(hid[i], 0.f);
        __syncthreads();
        const float* w2c = w2r + chunk * 256;
        for (int c = 0; c < 256; ++c) {
            float wv = w2c[c];
#pragma unroll
            for (int i = 0; i < 16; ++i) out[i] += hc[i][c] * wv;
        }
    }
    __syncthreads();
    for (int i = 0; i < 16; ++i) s2s[i][t] = out[i];
    __syncthreads();
    // LayerNorm
    int tok = t >> 4, j = t & 15;
    size_t gtok = (size_t)tile * 16 + tok;
    float sum = 0.f, ssq = 0.f;
    float vals[16];
#pragma unroll
    for (int d0 = 0; d0 < 16; ++d0) {
        int d = j + d0 * 16;
        float vv = hout[gtok * EMBEDc + d] + s2s[tok][d];
        vals[d0] = vv;
        sum += vv;
        ssq += vv * vv;
    }
#pragma unroll
    for (int off = 8; off; off >>= 1) {
        sum += __shfl_xor(sum, off, 16);
        ssq += __shfl_xor(ssq, off, 16);
    }
    float mean = sum * (1.f / EMBEDc);
    float var  = ssq * (1.f / EMBEDc) - mean * mean;
    float inv = rsqrtf(var + 1e-5f);
#pragma unroll
    for (int d0 = 0; d0 < 16; ++d0) {
        int d = j + d0 * 16;
        hout[gtok * EMBEDc + d] = (vals[d0] - mean) * inv * g[d] + bta[d];
    }
}

// ---------------------------------------------------------------------------
// K8: r = relu(h @ o_w1^T + o_b1) @ o_w2^T + o_b2   (one block / token)
__global__ __launch_bounds__(256) void k_final(const float* __restrict__ h,
                                               const float* __restrict__ w1,
                                               const float* __restrict__ b1,
                                               const float* __restrict__ w2,
                                               const float* __restrict__ b2,
                                               float* __restrict__ r) {
    int tok = blockIdx.x;
    int t = threadIdx.x;
    __shared__ float hs[EMBEDc];
    __shared__ float hid[EMBEDc];
    hs[t] = h[(size_t)tok * EMBEDc + t];
    __syncthreads();
    float s = b1[t];
    const float* w = w1 + (size_t)t * EMBEDc;
    for (int c = 0; c < EMBEDc; ++c) s += hs[c] * w[c];
    hid[t] = fmaxf(s, 0.f);
    __syncthreads();
    if (t < 3) {
        float o = b2[t];
        const float* wr = w2 + (size_t)t * EMBEDc;
        for (int c = 0; c < EMBEDc; ++c) o += hid[c] * wr[c];
        r[(size_t)tok * 3 + t] = o;
    }
}

// ---------------------------------------------------------------------------
// K9: pairwise distance map
__global__ __launch_bounds__(256) void k_dmap(const float* __restrict__ r,
                                              float* __restrict__ d) {
    int b = blockIdx.x;  // n*L + i
    int n = b / Lc;
    float xi = r[(size_t)b * 3], yi = r[(size_t)b * 3 + 1], zi = r[(size_t)b * 3 + 2];
    const float* rn = r + (size_t)n * Lc * 3;
    for (int j = threadIdx.x; j < Lc; j += 256) {
        float dx = xi - rn[j * 3];
        float dy = yi - rn[j * 3 + 1];
        float dz = zi - rn[j * 3 + 2];
        d[(size_t)b * Lc + j] = sqrtf(dx * dx + dy * dy + dz * dz + 1e-12f);
    }
}

// ---------------------------------------------------------------------------
extern "C" void kernel_launch(void* const* d_in, const int* in_sizes, int n_in,
                              void* d_out, int out_size, void* d_ws, size_t ws_size,
                              hipStream_t stream) {
    const float* z       = (const float*)d_in[0];
    const float* x       = (const float*)d_in[1];
    const float* pos_emb = (const float*)d_in[2];
    const float* aa_emb  = (const float*)d_in[3];
    const float* ex_w1   = (const float*)d_in[4];
    const float* ex_b1   = (const float*)d_in[5];
    const float* ex_w2   = (const float*)d_in[6];
    const float* ex_b2   = (const float*)d_in[7];
    const float* Wq      = (const float*)d_in[8];
    const float* Wk      = (const float*)d_in[9];
    const float* Wv      = (const float*)d_in[10];
    const float* Wo      = (const float*)d_in[11];
    const float* bo      = (const float*)d_in[12];
    const float* W2d     = (const float*)d_in[13];
    const float* b2d     = (const float*)d_in[14];
    const float* Wf1     = (const float*)d_in[15];
    const float* bf1     = (const float*)d_in[16];
    const float* Wf2     = (const float*)d_in[17];
    const float* bf2     = (const float*)d_in[18];
    const float* ln1_g   = (const float*)d_in[19];
    const float* ln1_b   = (const float*)d_in[20];
    const float* ln2_g   = (const float*)d_in[21];
    const float* ln2_b   = (const float*)d_in[22];
    const float* o_w1    = (const float*)d_in[23];
    const float* o_b1    = (const float*)d_in[24];
    const float* o_w2    = (const float*)d_in[25];
    const float* o_b2    = (const float*)d_in[26];

    float* ws = (float*)d_ws;
    float* h    = ws;                      // 4096*256
    float* q    = h    + (size_t)NTOK * EMBEDc;
    float* k    = q    + (size_t)NTOK * EMBEDc;
    float* v    = k    + (size_t)NTOK * EMBEDc;
    float* o    = v    + (size_t)NTOK * EMBEDc;
    float* eaa  = o    + (size_t)NTOK * EMBEDc;   // 4096*32
    float* bb   = eaa  + (size_t)NTOK * E1Dc;     // 6*16*49
    float* r    = bb   + NLc * NHc * NBINSc;      // 4096*3

    k_biasbins<<<(NLc * NHc * NBINSc + 255) / 256, 256, 0, stream>>>(pos_emb, W2d, b2d, bb);
    k_eaa<<<NTOK / 256, 256, 0, stream>>>(x, aa_emb, eaa);
    k_embed<<<NTOK, 256, 0, stream>>>(z, ex_w1, ex_b1, ex_w2, ex_b2, h);

    for (int l = 0; l < NLc; ++l) {
        const float* wq = Wq + (size_t)l * DMc * EMBEDc;
        const float* wk = Wk + (size_t)l * DMc * EMBEDc;
        const float* wv = Wv + (size_t)l * DMc * EMBEDc;
        const float* wo = Wo + (size_t)l * EMBEDc * DMc;
        k_qkv<<<NTOK / 16, 256, 0, stream>>>(h, wq, q, 0.0625f);   // 1/sqrt(256)
        k_qkv<<<NTOK / 16, 256, 0, stream>>>(h, wk, k, 1.0f);
        k_qkv<<<NTOK / 16, 256, 0, stream>>>(h, wv, v, 1.0f);
        k_attn<<<NB * NHc * (Lc / 16), 256, 0, stream>>>(q, k, v, bb + (size_t)l * NHc * NBINSc, o);
        k_oproj_ln<<<NTOK / 16, 256, 0, stream>>>(o, wo, bo + l * EMBEDc,
                                                  ln1_g + l * EMBEDc, ln1_b + l * EMBEDc, h);
        k_ffn_ln<<<NTOK / 16, 256, 0, stream>>>(h, eaa,
                                                Wf1 + (size_t)l * DFFc * UMDIM, bf1 + l * DFFc,
                                                Wf2 + (size_t)l * EMBEDc * DFFc, bf2 + l * EMBEDc,
                                                ln2_g + l * EMBEDc, ln2_b + l * EMBEDc, h);
    }

    k_final<<<NTOK, 256, 0, stream>>>(h, o_w1, o_b1, o_w2, o_b2, r);
    k_dmap<<<NB * Lc, 256, 0, stream>>>(r, (float*)d_out);
}